// Round 9
// baseline (286.908 us; speedup 1.0000x reference)
//
#include <hip/hip_runtime.h>

// Path signature M=4, d=10, L=256, B=2048 — MFMA formulation, round 9.
// S4[ij,kl] = sum_t b_t[ij] (v_t[k] v_t[l]) + a_t[ij] (v_t[k] R_t[l]),
// S3[ij,k]  = sum_t a_t[ij] v_t[k],  with
//   a_t = vivj/6 + S1_t[i] vj/2 + S2_t ;  b_t = vivj/24 + S1_t[i] vj/6 + S2_t/2
//   S1_t = x_t - x_0 (closed form), R_t = x_L - x_{t+1} (closed form),
//   S2 recurrence sequential (tiny, 100 lanes).
// GEMM C[112,112] = P^T Q, K = 4/t * 256 t-slots = 1024, bf16 hi/lo split on a,b.
// One block per batch. Per chunk (8 t, K=32): producer lanes fill P/Q (double-
// buffered, slot-major [slot][row][16B]) while all 4 waves MFMA the previous
// chunk. Producer roles spread across ALL waves: lane<25 -> pair (P-row),
// lane 25..52 -> Q-row (cell u/w or v-col). x-chain reads from global (L1),
// not LDS. Dead tiles skipped: waves do 16/12/12/9 MFMA (49 vs 64).

#define SIG 11110

typedef short bf16x8 __attribute__((ext_vector_type(8)));
typedef float f32x4  __attribute__((ext_vector_type(4)));

__device__ __forceinline__ unsigned cvt_pk2(float lo, float hi) {
    unsigned r;
    asm("v_cvt_pk_bf16_f32 %0, %1, %2" : "=v"(r) : "v"(lo), "v"(hi));
    return r;
}
// bf16 hi/lo split of one f32, packed as (hi | lo<<16)
__device__ __forceinline__ unsigned split_pack(float a) {
    unsigned t = cvt_pk2(a, a);
    float hi = __uint_as_float(t << 16);
    return cvt_pk2(a, a - hi);
}

template<int MI, int NI>
__device__ __forceinline__ void consume(const unsigned* __restrict__ Pb,
                                        const unsigned* __restrict__ Qb,
                                        int r0, int c0, int lane,
                                        f32x4 (&acc)[4][4]) {
    const int slot = lane >> 4, rr = lane & 15;
    bf16x8 Bf[4];
    #pragma unroll
    for (int ni = 0; ni < NI; ++ni)
        Bf[ni] = *(const bf16x8*)(Qb + slot * 512 + (c0 + ni * 16 + rr) * 4);
    #pragma unroll
    for (int mi = 0; mi < MI; ++mi) {
        const bf16x8 Af = *(const bf16x8*)(Pb + slot * 512 + (r0 + mi * 16 + rr) * 4);
        #pragma unroll
        for (int ni = 0; ni < NI; ++ni)
            acc[mi][ni] = __builtin_amdgcn_mfma_f32_16x16x32_bf16(Af, Bf[ni], acc[mi][ni], 0, 0, 0);
    }
}

__global__ __launch_bounds__(256, 2)
void sig_mfma2(const float* __restrict__ xg, float* __restrict__ out) {
    __shared__ unsigned Pl[2][2048];   // [buf][slot*512 + row*4 + w] : 8KB/buf
    __shared__ unsigned Ql[2][2048];
    const int tid  = threadIdx.x;
    const int b    = blockIdx.x;
    const int lane = tid & 63;
    const int wv   = tid >> 6;
    const float* __restrict__ xb = xg + (size_t)b * 2560;

    // zero pad rows once: P rows 100..127, Q rows 110..127 (both bufs, all slots)
    for (int e = tid; e < 896; e += 256) {
        const int buf = e / 448, r = e % 448, slot = r / 112, w = r % 112;
        Pl[buf][slot * 512 + (100 + w / 4) * 4 + (w & 3)] = 0u;
    }
    for (int e = tid; e < 576; e += 256) {
        const int buf = e / 288, r = e % 288, slot = r / 72, w = r % 72;
        Ql[buf][slot * 512 + (110 + w / 4) * 4 + (w & 3)] = 0u;
    }

    // producer roles (spread across all 4 waves for SIMD balance)
    const bool isPair = lane < 25;
    const int  p      = wv * 25 + lane;             // pair index (if isPair)
    const int  qq     = wv * 28 + (lane - 25);      // Q-row index
    const bool isQ    = (lane >= 25) && (lane < 53) && (qq < 110);
    const bool isCell = isQ && (qq < 100);
    const bool isVcol = isQ && (qq >= 100);

    int idx1 = 0, idx2 = 0;
    if (isPair)      { idx1 = p / 10;   idx2 = p - (p / 10) * 10; }
    else if (isCell) { idx1 = qq / 10;  idx2 = qq - (qq / 10) * 10; }
    else if (isVcol) { idx1 = qq - 100; idx2 = qq - 100; }

    float A  = xb[idx1];                 // chain: x_t[idx1]
    float Bv = xb[idx2];                 // chain: x_t[idx2]
    float C  = isCell ? xb[2550 + idx2] : A;  // cell: x_L[l]; pair: x_0[i]
    float Ds = 0.f;                      // pair: running S2

    f32x4 acc[4][4];
    #pragma unroll
    for (int mi = 0; mi < 4; ++mi)
        #pragma unroll
        for (int ni = 0; ni < 4; ++ni) acc[mi][ni] = (f32x4){0.f, 0.f, 0.f, 0.f};

    auto produce = [&](int ch, unsigned* Pb, unsigned* Qb) {
        unsigned w0 = 0, w1 = 0;
        #pragma unroll
        for (int tl = 0; tl < 8; ++tl) {
            const int  t     = ch * 8 + tl;
            const bool valid = (t < 255);
            const int  tt    = valid ? t : 254;
            const float n1 = xb[(tt + 1) * 10 + idx1];   // global (L1-resident)
            const float n2 = xb[(tt + 1) * 10 + idx2];
            const float v1 = n1 - A, v2 = n2 - Bv;
            unsigned o0, o1;
            if (isPair) {
                const float s1f  = A - C;
                const float vivj = v1 * v2;
                const float t1   = s1f * v2;
                float a  = fmaf(vivj, 1.f/6.f,  fmaf(t1, 0.5f,     Ds));
                float bb = fmaf(vivj, 1.f/24.f, fmaf(t1, 1.f/6.f,  0.5f * Ds));
                if (!valid) { a = 0.f; bb = 0.f; }
                o0 = split_pack(a); o1 = split_pack(bb);
                Ds = fmaf(v2, fmaf(v1, 0.5f, s1f), Ds);   // old S1 via s1f
            } else {
                const float u = v1 * (C - n2);            // v[k] * R_t[l]
                const float w = v1 * v2;                  // v[k] * v[l]
                o0 = isVcol ? cvt_pk2(v1, v1) : cvt_pk2(u, u);
                o1 = isVcol ? 0u              : cvt_pk2(w, w);
            }
            A = n1; Bv = n2;
            if ((tl & 1) == 0) { w0 = o0; w1 = o1; }
            else {
                const uint4 wq = make_uint4(w0, w1, o0, o1);
                if (isPair)   *(uint4*)(Pb + (tl >> 1) * 512 + p  * 4) = wq;
                else if (isQ) *(uint4*)(Qb + (tl >> 1) * 512 + qq * 4) = wq;
            }
        }
    };

    __syncthreads();                 // pads visible before first consume
    produce(0, Pl[0], Ql[0]);
    __syncthreads();

    for (int ch = 0; ch < 32; ++ch) {
        const unsigned* Pb = Pl[ch & 1];
        const unsigned* Qb = Ql[ch & 1];
        if      (wv == 0) consume<4, 4>(Pb, Qb,  0,  0, lane, acc);
        else if (wv == 1) consume<3, 4>(Pb, Qb, 64,  0, lane, acc);
        else if (wv == 2) consume<4, 3>(Pb, Qb,  0, 64, lane, acc);
        else              consume<3, 3>(Pb, Qb, 64, 64, lane, acc);
        if (ch < 31) produce(ch + 1, Pl[(ch + 1) & 1], Ql[(ch + 1) & 1]);
        __syncthreads();
    }

    // epilogue: [S1(10) | S2(100) | S3(1000) | S4(10000)]
    const size_t base = (size_t)b * SIG;
    if (tid < 10)  out[base + tid] = xb[2550 + tid] - xb[tid];   // S1 exact
    if (isPair)    out[base + 10 + p] = Ds;                      // S2 exact

    const int r0 = (wv & 1) * 64;
    const int c0 = (wv >> 1) * 64;
    #pragma unroll
    for (int mi = 0; mi < 4; ++mi) {
        #pragma unroll
        for (int ni = 0; ni < 4; ++ni) {
            #pragma unroll
            for (int r = 0; r < 4; ++r) {
                const int m = r0 + mi * 16 + (lane >> 4) * 4 + r;
                const int n = c0 + ni * 16 + (lane & 15);
                if (m < 100) {
                    if (n < 100)      out[base + 1110 + m * 100 + n]         = acc[mi][ni][r];
                    else if (n < 110) out[base + 110  + m * 10  + (n - 100)] = acc[mi][ni][r];
                }
            }
        }
    }
}

extern "C" void kernel_launch(void* const* d_in, const int* in_sizes, int n_in,
                              void* d_out, int out_size, void* d_ws, size_t ws_size,
                              hipStream_t stream) {
    const float* x = (const float*)d_in[0];
    float* out = (float*)d_out;
    const int B = in_sizes[0] / 2560;   // 2048 batches, one block each
    sig_mfma2<<<B, 256, 0, stream>>>(x, out);
}

// Round 10
// 254.377 us; speedup vs baseline: 1.1279x; 1.1279x over previous
//
#include <hip/hip_runtime.h>

// Path signature M=4, d=10, L=256, B=2048 — MFMA formulation, round 10.
// Math identical to rounds 8/9 (absmax 13 verified):
//   S4[ij,kl] = sum_t b_t[ij](v_t[k]v_t[l]) + a_t[ij](v_t[k]R_t[l]);  S3 via v-cols.
//   a_t = vivj/6 + S1_t[i]vj/2 + S2_t ;  b_t = vivj/24 + S1_t[i]vj/6 + S2_t/2
// GEMM C[112,112] = P^T Q, K=1024 (4 K-rows/t: a_hi,a_lo,b_hi,b_lo vs u,u,w,w).
// Round-10 structure: per chunk (8 t), 3 stages:
//   A (110 lanes): sequential-only math -> AB[tl][pair]={a,b} f32, VR[tl][dim]={v,R}
//   B (ALL 256 lanes, 1680 items): cvt_pk bf16 split-pack -> P/Q slot-major
//   C (4 waves): MFMA, dead tiles skipped (16/12/12/9)
// This moves the packing off the serial producer and onto all 4 SIMDs.
// P/Q slot-major [slot][112 rows][16B] -> conflict-free b128 frag reads (r9: 10x fewer).

#define SIG 11110

typedef short bf16x8 __attribute__((ext_vector_type(8)));
typedef float f32x4  __attribute__((ext_vector_type(4)));

__device__ __forceinline__ unsigned cvt_pk2(float lo, float hi) {
    unsigned r;
    asm("v_cvt_pk_bf16_f32 %0, %1, %2" : "=v"(r) : "v"(lo), "v"(hi));
    return r;
}
// (bf16(a) | bf16(a - bf16(a))<<16)  — hi/lo split, 4 VALU
__device__ __forceinline__ unsigned split_pack(float a) {
    unsigned t = cvt_pk2(a, a);
    float hi = __uint_as_float(t << 16);
    return cvt_pk2(a, a - hi);
}

template<int MI, int NI>
__device__ __forceinline__ void consume(const unsigned* __restrict__ Pb,
                                        const unsigned* __restrict__ Qb,
                                        int r0, int c0, int lane,
                                        f32x4 (&acc)[4][4]) {
    const int slot = lane >> 4, rr = lane & 15;
    bf16x8 Bf[4];
    #pragma unroll
    for (int ni = 0; ni < NI; ++ni)
        Bf[ni] = *(const bf16x8*)(Qb + slot * 448 + (c0 + ni * 16 + rr) * 4);
    #pragma unroll
    for (int mi = 0; mi < MI; ++mi) {
        const bf16x8 Af = *(const bf16x8*)(Pb + slot * 448 + (r0 + mi * 16 + rr) * 4);
        #pragma unroll
        for (int ni = 0; ni < NI; ++ni)
            acc[mi][ni] = __builtin_amdgcn_mfma_f32_16x16x32_bf16(Af, Bf[ni], acc[mi][ni], 0, 0, 0);
    }
}

__global__ __launch_bounds__(256, 3)
void sig_mfma3(const float* __restrict__ xg, float* __restrict__ out) {
    __shared__ float    xs[2560];          // path, [t*10+dim]
    __shared__ float2   AB[800];           // [tl*100+pair] = {a, b} fp32
    __shared__ float2   VR[80];            // [tl*10+dim]   = {v_t[dim], R_t[dim]}
    __shared__ unsigned Pl[4 * 448];       // [slot][112 rows][4 words]
    __shared__ unsigned Ql[4 * 448];

    const int tid  = threadIdx.x;
    const int b    = blockIdx.x;
    const int lane = tid & 63;
    const int wv   = tid >> 6;
    const float* __restrict__ xb = xg + (size_t)b * 2560;

    // stage x (coalesced) + zero pad rows (P rows 100..111, Q rows 110..111)
    #pragma unroll
    for (int r = 0; r < 10; ++r) xs[r * 256 + tid] = xb[r * 256 + tid];
    if (tid < 224) {
        if (tid < 192) {
            const int slot = tid / 48, rem = tid % 48;
            Pl[slot * 448 + (100 + rem / 4) * 4 + (rem & 3)] = 0u;
        } else {
            const int e = tid - 192;               // 32 words
            const int slot = e / 8, rem = e % 8;
            Ql[slot * 448 + (110 + rem / 4) * 4 + (rem & 3)] = 0u;
        }
    }
    __syncthreads();

    // producer state
    int i = 0, j = 0;
    float xti = 0, xtj = 0, x0i = 0, Ds = 0, xcv = 0, xLd = 0;
    if (tid < 100) {
        i = tid / 10; j = tid - i * 10;
        xti = xs[i]; xtj = xs[j]; x0i = xti;
    } else if (tid < 110) {
        const int d = tid - 100;
        xcv = xs[d]; xLd = xs[2550 + d];
    }

    f32x4 acc[4][4];
    #pragma unroll
    for (int mi = 0; mi < 4; ++mi)
        #pragma unroll
        for (int ni = 0; ni < 4; ++ni) acc[mi][ni] = (f32x4){0.f, 0.f, 0.f, 0.f};

    for (int ch = 0; ch < 32; ++ch) {
        // ---- stage A: sequential math only (110 lanes) ----
        if (tid < 100) {
            #pragma unroll
            for (int tl = 0; tl < 8; ++tl) {
                const int  t     = ch * 8 + tl;
                const bool valid = (t < 255);
                const int  tt    = valid ? t : 254;
                const float xt1i = xs[(tt + 1) * 10 + i];
                const float xt1j = xs[(tt + 1) * 10 + j];
                const float vi = xt1i - xti, vj = xt1j - xtj;
                const float s1f  = xti - x0i;
                const float vivj = vi * vj;
                const float t1   = s1f * vj;
                float a  = fmaf(vivj, 1.f/6.f,  fmaf(t1, 0.5f,    Ds));
                float bb = fmaf(vivj, 1.f/24.f, fmaf(t1, 1.f/6.f, 0.5f * Ds));
                if (!valid) { a = 0.f; bb = 0.f; }
                AB[tl * 100 + tid] = make_float2(a, bb);
                if (valid) {
                    Ds = fmaf(vj, fmaf(vi, 0.5f, s1f), Ds);
                    xti = xt1i; xtj = xt1j;
                }
            }
        } else if (tid < 110) {
            const int d = tid - 100;
            #pragma unroll
            for (int tl = 0; tl < 8; ++tl) {
                const int  t     = ch * 8 + tl;
                const bool valid = (t < 255);
                const int  tt    = valid ? t : 254;
                const float xn = xs[(tt + 1) * 10 + d];
                const float v  = valid ? (xn - xcv) : 0.f;
                const float R  = xLd - xn;
                VR[tl * 10 + d] = make_float2(v, R);
                if (valid) xcv = xn;
            }
        }
        __syncthreads();
        // ---- stage B: pack to bf16, ALL lanes (1680 items) ----
        for (int e = tid; e < 1680; e += 256) {
            if (e < 800) {                       // P rows (pairs)
                const int tl = e / 100, row = e - tl * 100;
                const float2 ab = AB[tl * 100 + row];
                *(uint2*)&Pl[(tl >> 1) * 448 + row * 4 + (tl & 1) * 2] =
                    make_uint2(split_pack(ab.x), split_pack(ab.y));
            } else if (e < 1600) {               // Q rows (cells kl)
                const int eq = e - 800;
                const int tl = eq / 100, cell = eq - tl * 100;
                const int k = cell / 10, l = cell - k * 10;
                const float2 vr_l = VR[tl * 10 + l];
                const float  v_k  = VR[tl * 10 + k].x;
                const float u = v_k * vr_l.y, w = v_k * vr_l.x;
                *(uint2*)&Ql[(tl >> 1) * 448 + cell * 4 + (tl & 1) * 2] =
                    make_uint2(cvt_pk2(u, u), cvt_pk2(w, w));
            } else {                             // Q v-cols (S3)
                const int ev = e - 1600;
                const int tl = ev / 10, d = ev - tl * 10;
                const float v = VR[tl * 10 + d].x;
                *(uint2*)&Ql[(tl >> 1) * 448 + (100 + d) * 4 + (tl & 1) * 2] =
                    make_uint2(cvt_pk2(v, v), 0u);
            }
        }
        __syncthreads();
        // ---- stage C: MFMA (dead tiles skipped) ----
        if      (wv == 0) consume<4, 4>(Pl, Ql,  0,  0, lane, acc);
        else if (wv == 1) consume<3, 4>(Pl, Ql, 64,  0, lane, acc);
        else if (wv == 2) consume<4, 3>(Pl, Ql,  0, 64, lane, acc);
        else              consume<3, 3>(Pl, Ql, 64, 64, lane, acc);
        __syncthreads();
    }

    // ---- epilogue: [S1(10) | S2(100) | S3(1000) | S4(10000)] ----
    const size_t base = (size_t)b * SIG;
    if (tid < 10)  out[base + tid] = xs[2550 + tid] - xs[tid];   // S1 exact
    if (tid < 100) out[base + 10 + tid] = Ds;                    // S2 exact

    const int r0 = (wv & 1) * 64;
    const int c0 = (wv >> 1) * 64;
    #pragma unroll
    for (int mi = 0; mi < 4; ++mi) {
        #pragma unroll
        for (int ni = 0; ni < 4; ++ni) {
            #pragma unroll
            for (int r = 0; r < 4; ++r) {
                const int m = r0 + mi * 16 + (lane >> 4) * 4 + r;
                const int n = c0 + ni * 16 + (lane & 15);
                if (m < 100) {
                    if (n < 100)      out[base + 1110 + m * 100 + n]         = acc[mi][ni][r];
                    else if (n < 110) out[base + 110  + m * 10  + (n - 100)] = acc[mi][ni][r];
                }
            }
        }
    }
}

extern "C" void kernel_launch(void* const* d_in, const int* in_sizes, int n_in,
                              void* d_out, int out_size, void* d_ws, size_t ws_size,
                              hipStream_t stream) {
    const float* x = (const float*)d_in[0];
    float* out = (float*)d_out;
    const int B = in_sizes[0] / 2560;   // 2048 batches, one block each
    sig_mfma3<<<B, 256, 0, stream>>>(x, out);
}

// Round 11
// 126.971 us; speedup vs baseline: 2.2596x; 2.0034x over previous
//
#include <hip/hip_runtime.h>

// Path signature M=4, d=10, L=256, B=2048 — MFMA formulation, round 11.
// Math identical to rounds 8-10 (absmax 13):
//   S4[ij,kl] = sum_t b_t[ij](v_t[k]v_t[l]) + a_t[ij](v_t[k]R_t[l]);  S3 via v-cols.
//   a_t = vivj/6 + S1_t[i]vj/2 + S2_t ;  b_t = vivj/24 + S1_t[i]vj/6 + S2_t/2
//   S1_t, R_t closed-form; S2 sequential scan (pair lanes only).
// C[112,112] = P^T Q, K=1024 (per t: K-rows a_hi,a_lo,b_hi,b_lo vs u,u,w,w).
// Round-11 structure (round 8 skeleton + proven fixes):
//  - slot-major P/Q [slot][112 rows][16B]: conflict-free b128 reads AND writes
//    (round 9 measured 8.4M -> 0.8M conflicts with this layout)
//  - cvt_pk split-pack: 4 insts vs ~12 manual RNE
//  - producer on ALL SIMDs: waves 0-1 = pair scan -> P; waves 2-3 = closed-form
//    cell/vcol rows -> Q. MFMA tiles swapped: lightest producer gets <4,4>.

#define SIG 11110

typedef short bf16x8 __attribute__((ext_vector_type(8)));
typedef float f32x4  __attribute__((ext_vector_type(4)));

__device__ __forceinline__ unsigned cvt_pk2(float lo, float hi) {
    unsigned r;
    asm("v_cvt_pk_bf16_f32 %0, %1, %2" : "=v"(r) : "v"(lo), "v"(hi));
    return r;
}
// (bf16(a) | bf16(a - bf16(a))<<16) — hi/lo split
__device__ __forceinline__ unsigned split_pack(float a) {
    unsigned t = cvt_pk2(a, a);
    float hi = __uint_as_float(t << 16);
    return cvt_pk2(a, a - hi);
}

template<int MI, int NI>
__device__ __forceinline__ void consume(const unsigned* __restrict__ Pb,
                                        const unsigned* __restrict__ Qb,
                                        int r0, int c0, int lane,
                                        f32x4 (&acc)[4][4]) {
    const int slot = lane >> 4, rr = lane & 15;
    bf16x8 Bf[4];
    #pragma unroll
    for (int ni = 0; ni < NI; ++ni)
        Bf[ni] = *(const bf16x8*)(Qb + slot * 448 + (c0 + ni * 16 + rr) * 4);
    #pragma unroll
    for (int mi = 0; mi < MI; ++mi) {
        const bf16x8 Af = *(const bf16x8*)(Pb + slot * 448 + (r0 + mi * 16 + rr) * 4);
        #pragma unroll
        for (int ni = 0; ni < NI; ++ni)
            acc[mi][ni] = __builtin_amdgcn_mfma_f32_16x16x32_bf16(Af, Bf[ni], acc[mi][ni], 0, 0, 0);
    }
}

__global__ __launch_bounds__(256, 3)
void sig_mfma4(const float* __restrict__ xg, float* __restrict__ out) {
    __shared__ float    xs[2560];      // path [t*10+dim]
    __shared__ unsigned Pl[4 * 448];   // [slot][112 rows][4 words] 7168B
    __shared__ unsigned Ql[4 * 448];

    const int tid  = threadIdx.x;
    const int b    = blockIdx.x;
    const int lane = tid & 63;
    const int wv   = tid >> 6;
    const float* __restrict__ xb = xg + (size_t)b * 2560;

    // stage path (coalesced) + zero pads (P rows 100..111, Q rows 110..111)
    #pragma unroll
    for (int r = 0; r < 10; ++r) xs[r * 256 + tid] = xb[r * 256 + tid];
    if (tid < 192) Pl[(tid / 48) * 448 + (100 + (tid % 48) / 4) * 4 + (tid & 3)] = 0u;
    if (tid < 32)  Ql[(tid / 8)  * 448 + (110 + (tid % 8)  / 4) * 4 + (tid & 3)] = 0u;
    __syncthreads();

    // roles
    const bool isPair = (tid < 100);            // waves 0-1: sequential scan -> P
    const int  qrow   = tid - 128;              // waves 2-3: closed-form -> Q
    const bool isCell = (qrow >= 0) && (qrow < 100);
    const bool isVcol = (qrow >= 100) && (qrow < 110);

    int i1 = 0, i2 = 0;
    if (isPair)      { i1 = tid / 10;  i2 = tid - i1 * 10; }
    else if (isCell) { i1 = qrow / 10; i2 = qrow - i1 * 10; }
    else if (isVcol) { i1 = qrow - 100; i2 = i1; }

    float c1 = xs[i1], c2 = xs[i2];             // chains x_t[i1], x_t[i2]
    const float x0i = c1;
    const float xL2 = xs[2550 + i2];            // cells: x_L[l]
    float Ds = 0.f;                              // pairs: running S2

    f32x4 acc[4][4];
    #pragma unroll
    for (int mi = 0; mi < 4; ++mi)
        #pragma unroll
        for (int ni = 0; ni < 4; ++ni) acc[mi][ni] = (f32x4){0.f, 0.f, 0.f, 0.f};

    for (int ch = 0; ch < 32; ++ch) {
        if (isPair) {
            unsigned q0 = 0, q1 = 0;
            #pragma unroll
            for (int tl = 0; tl < 8; ++tl) {
                const int  t     = ch * 8 + tl;
                const bool valid = (t < 255);
                const int  tt    = valid ? t : 254;
                const float n1 = xs[(tt + 1) * 10 + i1];
                const float n2 = xs[(tt + 1) * 10 + i2];
                const float vi = n1 - c1, vj = n2 - c2;
                const float s1f  = c1 - x0i;
                const float vivj = vi * vj;
                const float t1   = s1f * vj;
                float a  = fmaf(vivj, 1.f/6.f,  fmaf(t1, 0.5f,    Ds));
                float bb = fmaf(vivj, 1.f/24.f, fmaf(t1, 1.f/6.f, 0.5f * Ds));
                if (!valid) { a = 0.f; bb = 0.f; }
                const unsigned pa = split_pack(a), pb = split_pack(bb);
                if (valid) { Ds = fmaf(vj, fmaf(vi, 0.5f, s1f), Ds); c1 = n1; c2 = n2; }
                if ((tl & 1) == 0) { q0 = pa; q1 = pb; }
                else *(uint4*)&Pl[(tl >> 1) * 448 + tid * 4] = make_uint4(q0, q1, pa, pb);
            }
        } else if (isCell) {
            unsigned q0 = 0, q1 = 0;
            #pragma unroll
            for (int tl = 0; tl < 8; ++tl) {
                const int  t     = ch * 8 + tl;
                const bool valid = (t < 255);
                const int  tt    = valid ? t : 254;
                const float n1 = xs[(tt + 1) * 10 + i1];
                const float n2 = xs[(tt + 1) * 10 + i2];
                const float vk = n1 - c1, vl = n2 - c2;
                float u = vk * (xL2 - n2);
                float w = vk * vl;
                if (!valid) { u = 0.f; w = 0.f; }
                const unsigned pu = cvt_pk2(u, u), pw = cvt_pk2(w, w);
                if (valid) { c1 = n1; c2 = n2; }
                if ((tl & 1) == 0) { q0 = pu; q1 = pw; }
                else *(uint4*)&Ql[(tl >> 1) * 448 + qrow * 4] = make_uint4(q0, q1, pu, pw);
            }
        } else if (isVcol) {
            unsigned q0 = 0;
            #pragma unroll
            for (int tl = 0; tl < 8; ++tl) {
                const int  t     = ch * 8 + tl;
                const bool valid = (t < 255);
                const int  tt    = valid ? t : 254;
                const float n1 = xs[(tt + 1) * 10 + i1];
                float v = n1 - c1;
                if (!valid) v = 0.f;
                const unsigned pv = cvt_pk2(v, v);
                if (valid) c1 = n1;
                if ((tl & 1) == 0) q0 = pv;
                else *(uint4*)&Ql[(tl >> 1) * 448 + qrow * 4] = make_uint4(q0, 0u, pv, 0u);
            }
        }
        __syncthreads();
        // MFMA: lightest producer wave gets the biggest tile block
        if      (wv == 0) consume<3, 3>(Pl, Ql, 64, 64, lane, acc);   //  9 tiles
        else if (wv == 1) consume<3, 4>(Pl, Ql, 64,  0, lane, acc);   // 12
        else if (wv == 2) consume<4, 3>(Pl, Ql,  0, 64, lane, acc);   // 12
        else              consume<4, 4>(Pl, Ql,  0,  0, lane, acc);   // 16
        __syncthreads();
    }

    // epilogue: [S1(10) | S2(100) | S3(1000) | S4(10000)]
    const size_t base = (size_t)b * SIG;
    if (tid < 10)  out[base + tid] = xs[2550 + tid] - xs[tid];   // S1 exact
    if (isPair)    out[base + 10 + tid] = Ds;                    // S2 exact

    const int r0 = (wv & 2) ? 0 : 64;
    const int c0 = (wv & 1) ? 0 : 64;
    #pragma unroll
    for (int mi = 0; mi < 4; ++mi) {
        #pragma unroll
        for (int ni = 0; ni < 4; ++ni) {
            #pragma unroll
            for (int r = 0; r < 4; ++r) {
                const int m = r0 + mi * 16 + (lane >> 4) * 4 + r;
                const int n = c0 + ni * 16 + (lane & 15);
                if (m < 100) {
                    if (n < 100)      out[base + 1110 + m * 100 + n]         = acc[mi][ni][r];
                    else if (n < 110) out[base + 110  + m * 10  + (n - 100)] = acc[mi][ni][r];
                }
            }
        }
    }
}

extern "C" void kernel_launch(void* const* d_in, const int* in_sizes, int n_in,
                              void* d_out, int out_size, void* d_ws, size_t ws_size,
                              hipStream_t stream) {
    const float* x = (const float*)d_in[0];
    float* out = (float*)d_out;
    const int B = in_sizes[0] / 2560;   // 2048 batches, one block each
    sig_mfma4<<<B, 256, 0, stream>>>(x, out);
}